// Round 3
// baseline (206.175 us; speedup 1.0000x reference)
//
#include <hip/hip_runtime.h>

typedef unsigned short u16;
typedef unsigned int   u32;
typedef __bf16 bf16x8 __attribute__((ext_vector_type(8)));
typedef float  f32x4  __attribute__((ext_vector_type(4)));

#define B_DIM 2
#define T_DIM 2048
#define C_DIM 768
#define H_DIM 12
#define D_DIM 64
#define KD 768  // GEMM K dim (= C)

__device__ __forceinline__ u16 f2bf(float f) {
    union { float f; u32 u; } v; v.f = f;
    u32 r = v.u + 0x7FFFu + ((v.u >> 16) & 1u);   // RNE
    return (u16)(r >> 16);
}

__device__ __forceinline__ u32 cvt_pk_bf16(float lo, float hi) {
    u32 r;
    asm("v_cvt_pk_bf16_f32 %0, %1, %2" : "=v"(r) : "v"(lo), "v"(hi));
    return r;
}

__device__ __forceinline__ float exp2_hw(float x) {
    float r;
    asm("v_exp_f32 %0, %1" : "=v"(r) : "v"(x));
    return r;
}

__device__ __forceinline__ void load_lds16(const void* g, void* l) {
    __builtin_amdgcn_global_load_lds(
        (const __attribute__((address_space(1))) u32*)g,
        (__attribute__((address_space(3))) u32*)l,
        16, 0, 0);
}

// ---------------- fp32 -> bf16 convert (x) ----------------
__global__ __launch_bounds__(256) void convert_bf16(const float* __restrict__ in,
                                                    u16* __restrict__ out) {
    int i = blockIdx.x * blockDim.x + threadIdx.x;   // grid sized exactly: n/4 threads
    float4 v = ((const float4*)in)[i];
    ushort4 o;
    o.x = f2bf(v.x); o.y = f2bf(v.y); o.z = f2bf(v.z); o.w = f2bf(v.w);
    ((ushort4*)out)[i] = o;
}

// ---------------- W [K][N] fp32 -> Wt [N][K] bf16 ----------------
__global__ __launch_bounds__(256) void transpose_bf16(const float* __restrict__ W,
                                                      u16* __restrict__ Wt,
                                                      int K, int N) {
    __shared__ float tile[32][33];
    int bx = blockIdx.x * 32, by = blockIdx.y * 32;
    int tx = threadIdx.x, ty = threadIdx.y;
#pragma unroll
    for (int i = ty; i < 32; i += 8) tile[i][tx] = W[(size_t)(by + i) * N + bx + tx];
    __syncthreads();
#pragma unroll
    for (int i = ty; i < 32; i += 8) Wt[(size_t)(bx + i) * K + by + tx] = f2bf(tile[tx][i]);
}

// ---------------- GEMM: A[M][768] bf16 @ Bt[N][768]^T, 128 x (NJ*32) tile, BK=64 ----------------
// 4 waves as 2x2; each wave owns 64 x (NJ*16).
// EPI 0: scatter into Q (scaled), K, Vt buffers (bf16).  EPI 1: fp32 out + bias.
template <int EPI, int NJ>
__global__ __launch_bounds__(256)
void gemm_bt(const u16* __restrict__ A, const u16* __restrict__ Bt,
             const float* __restrict__ bias,
             u16* __restrict__ Qb, u16* __restrict__ Kb, u16* __restrict__ Vt,
             float* __restrict__ Cout) {
    __shared__ u16 lA[128 * 64];
    __shared__ u16 lB[NJ * 32 * 64];
    const int tid  = threadIdx.x;
    const int lane = tid & 63, wv = tid >> 6;
    const int lr = lane & 15, lg = lane >> 4;
    const int wm = wv >> 1, wn = wv & 1;
    const int row0 = blockIdx.y * 128, col0 = blockIdx.x * (NJ * 32);

    const f32x4 Z4 = {0.f, 0.f, 0.f, 0.f};
    f32x4 acc[4][NJ];
#pragma unroll
    for (int i = 0; i < 4; i++)
#pragma unroll
        for (int j = 0; j < NJ; j++) acc[i][j] = Z4;

    for (int kt = 0; kt < KD / 64; ++kt) {
#pragma unroll
        for (int i = 0; i < 4; i++) {               // A: 16 chunks of 1KB
            int chunk = wv * 4 + i;
            int row = chunk * 8 + (lane >> 3);
            int el  = (lane & 7) * 8;
            load_lds16(&A[(size_t)(row0 + row) * KD + kt * 64 + el], &lA[chunk * 512]);
        }
#pragma unroll
        for (int i = 0; i < NJ; i++) {              // B: NJ*4 chunks of 1KB
            int chunk = wv * NJ + i;
            int row = chunk * 8 + (lane >> 3);
            int el  = (lane & 7) * 8;
            load_lds16(&Bt[(size_t)(col0 + row) * KD + kt * 64 + el], &lB[chunk * 512]);
        }
        __syncthreads();
#pragma unroll
        for (int kk = 0; kk < 2; kk++) {
            bf16x8 af[4], bfr[NJ];
#pragma unroll
            for (int i = 0; i < 4; i++)
                af[i] = *(const bf16x8*)&lA[(wm * 64 + i * 16 + lr) * 64 + kk * 32 + lg * 8];
#pragma unroll
            for (int j = 0; j < NJ; j++)
                bfr[j] = *(const bf16x8*)&lB[(wn * (NJ * 16) + j * 16 + lr) * 64 + kk * 32 + lg * 8];
#pragma unroll
            for (int i = 0; i < 4; i++)
#pragma unroll
                for (int j = 0; j < NJ; j++)
                    acc[i][j] = __builtin_amdgcn_mfma_f32_16x16x32_bf16(af[i], bfr[j], acc[i][j], 0, 0, 0);
        }
        __syncthreads();
    }

    if (EPI == 0) {
        // qkv scatter.  col tile (NJ*32 | 64) lies fully inside one of q/k/v segments.
        const int b  = row0 >> 11;
        const int t0 = (row0 & 2047) + wm * 64;
        const float qscale = 0.125f * 1.44269504088896340736f;  // fold log2(e): softmax in exp2 domain
#pragma unroll
        for (int i = 0; i < 4; i++) {
#pragma unroll
            for (int j = 0; j < NJ; j++) {
                const int n   = col0 + wn * (NJ * 16) + j * 16 + lr;
                const int seg = n / 768;
                const int nn  = n - seg * 768;
                const int h   = nn >> 6;
                const int d   = nn & 63;
                const float bv = bias[n];
#pragma unroll
                for (int r = 0; r < 4; r++) {
                    const int t = t0 + i * 16 + lg * 4 + r;
                    float v = acc[i][j][r] + bv;
                    if (seg == 0) {
                        Qb[((size_t)(b * H_DIM + h) * T_DIM + t) * D_DIM + d] = f2bf(v * qscale);
                    } else if (seg == 1) {
                        Kb[((size_t)(b * H_DIM + h) * T_DIM + t) * D_DIM + d] = f2bf(v);
                    } else {
                        Vt[((size_t)(b * H_DIM + h) * D_DIM + d) * T_DIM + t] = f2bf(v);
                    }
                }
            }
        }
    } else {
#pragma unroll
        for (int i = 0; i < 4; i++)
#pragma unroll
            for (int j = 0; j < NJ; j++) {
                const int n  = col0 + wn * (NJ * 16) + j * 16 + lr;
                const float bv = bias[n];
#pragma unroll
                for (int r = 0; r < 4; r++) {
                    const int m = row0 + wm * 64 + i * 16 + lg * 4 + r;
                    Cout[(size_t)m * 768 + n] = acc[i][j][r] + bv;
                }
            }
    }
}

// ---------------- causal flash attention (swapped-operand, zero-LDS) ----------------
// 1 wave per block, 16 q-rows per wave.  grid (B*H, T/16), LPT order (longest first).
// S^T = mfma(K,Q): lane holds q = qbase+(lane&15), k = kc+kf*16+4*lg+r.
// PV uses contraction-order freedom: B-frag (P^T) slots come straight from the lane's
// own registers; V A-frag is loaded with the matching permuted t-offsets.
struct KTile { bf16x8 k[4][2]; };
struct VTile { ushort4 v[4][2][2]; };   // [d-tile n][K32-step s][chunk]
union VFrag  { struct { ushort4 lo, hi; } s; bf16x8 v; };
union PFrag  { u32 w[4]; bf16x8 v; };

__global__ __launch_bounds__(64)
void attn_kernel(const u16* __restrict__ Qb, const u16* __restrict__ Kb,
                 const u16* __restrict__ Vt, u16* __restrict__ Yb) {
    const int bh    = blockIdx.x;
    const int chunk = (int)gridDim.y - 1 - blockIdx.y;   // LPT: longest q-chunks first
    const int b = bh / H_DIM, h = bh % H_DIM;
    const int lane = threadIdx.x;
    const int lr = lane & 15, lg = lane >> 4;
    const int qbase = chunk * 16;
    const int kend  = qbase + 16;

    const u16* Qp = Qb + (size_t)bh * T_DIM * D_DIM;
    const u16* Kp = Kb + (size_t)bh * T_DIM * D_DIM;
    const u16* Vp = Vt + (size_t)bh * D_DIM * T_DIM;

    // Q fragments (B-operand): col = lr = q-within-16, contraction d = lg*8+j
    bf16x8 qf[2];
#pragma unroll
    for (int dh = 0; dh < 2; dh++)
        qf[dh] = *(const bf16x8*)&Qp[(size_t)(qbase + lr) * 64 + dh * 32 + lg * 8];

    const f32x4 Z4 = {0.f, 0.f, 0.f, 0.f};
    f32x4 yacc[4];                  // [n]: col q = lr, row d = n*16 + 4*lg + r
    float mrun = -1e30f, lrun = 0.f;
#pragma unroll
    for (int n = 0; n < 4; n++) yacc[n] = Z4;

    auto load_k = [&](KTile& kt, int kc) {
#pragma unroll
        for (int kf = 0; kf < 4; kf++)
#pragma unroll
            for (int dh = 0; dh < 2; dh++)
                kt.k[kf][dh] = *(const bf16x8*)&Kp[(size_t)(kc + kf * 16 + lr) * 64 + dh * 32 + lg * 8];
    };

    auto process = [&](KTile& kt, int kc) {
        // V loads issued first: consumed only after softmax (~600 cyc of overlap)
        VTile vt;
#pragma unroll
        for (int n = 0; n < 4; n++)
#pragma unroll
            for (int s = 0; s < 2; s++)
#pragma unroll
                for (int c = 0; c < 2; c++)
                    vt.v[n][s][c] = *(const ushort4*)&Vp[(size_t)(n * 16 + lr) * T_DIM + kc + 32 * s + 16 * c + 4 * lg];

        // ---- S^T = K @ Q^T ----
        f32x4 ST[4];
#pragma unroll
        for (int kf = 0; kf < 4; kf++) ST[kf] = Z4;
        __builtin_amdgcn_s_setprio(1);
#pragma unroll
        for (int kf = 0; kf < 4; kf++) {
            ST[kf] = __builtin_amdgcn_mfma_f32_16x16x32_bf16(kt.k[kf][0], qf[0], ST[kf], 0, 0, 0);
            ST[kf] = __builtin_amdgcn_mfma_f32_16x16x32_bf16(kt.k[kf][1], qf[1], ST[kf], 0, 0, 0);
        }
        __builtin_amdgcn_s_setprio(0);

        // ---- causal mask (diagonal-crossing tiles only) ----
        if (kc + 63 > qbase) {
            const int q = qbase + lr;
#pragma unroll
            for (int kf = 0; kf < 4; kf++)
#pragma unroll
                for (int r = 0; r < 4; r++) {
                    const int k = kc + kf * 16 + 4 * lg + r;
                    if (k > q) ST[kf][r] = -1e30f;
                }
        }

        // ---- online softmax (per lane: one q-col, 16 k-values) ----
        float mx = -1e30f;
#pragma unroll
        for (int kf = 0; kf < 4; kf++) {
            float a = fmaxf(ST[kf][0], ST[kf][1]);
            float c = fmaxf(ST[kf][2], ST[kf][3]);
            mx = fmaxf(mx, fmaxf(a, c));
        }
        mx = fmaxf(mx, __shfl_xor(mx, 16));
        mx = fmaxf(mx, __shfl_xor(mx, 32));
        const float mnew = fmaxf(mrun, mx);
        const float sfr  = exp2_hw(mrun - mnew);
        mrun = mnew;
        float sum = 0.f;
#pragma unroll
        for (int kf = 0; kf < 4; kf++)
#pragma unroll
            for (int r = 0; r < 4; r++) {
                float p = exp2_hw(ST[kf][r] - mnew);
                ST[kf][r] = p;
                sum += p;
            }
        sum += __shfl_xor(sum, 16);
        sum += __shfl_xor(sum, 32);
        lrun = lrun * sfr + sum;
#pragma unroll
        for (int n = 0; n < 4; n++)
#pragma unroll
            for (int r = 0; r < 4; r++) yacc[n][r] *= sfr;
        // pack P -> bf16, own-register slot map (k = 32s + 4*lg + j pattern)
        PFrag pf[2];
#pragma unroll
        for (int s = 0; s < 2; s++) {
            pf[s].w[0] = cvt_pk_bf16(ST[2 * s][0],     ST[2 * s][1]);
            pf[s].w[1] = cvt_pk_bf16(ST[2 * s][2],     ST[2 * s][3]);
            pf[s].w[2] = cvt_pk_bf16(ST[2 * s + 1][0], ST[2 * s + 1][1]);
            pf[s].w[3] = cvt_pk_bf16(ST[2 * s + 1][2], ST[2 * s + 1][3]);
        }

        // ---- y^T += V^T @ P^T ----
        __builtin_amdgcn_s_setprio(1);
#pragma unroll
        for (int s = 0; s < 2; s++)
#pragma unroll
            for (int n = 0; n < 4; n++) {
                VFrag av;
                av.s.lo = vt.v[n][s][0];
                av.s.hi = vt.v[n][s][1];
                yacc[n] = __builtin_amdgcn_mfma_f32_16x16x32_bf16(av.v, pf[s].v, yacc[n], 0, 0, 0);
            }
        __builtin_amdgcn_s_setprio(0);
    };

    // ---- K-prefetch double-buffered k-loop ----
    KTile kA, kB;
    load_k(kA, 0);
    int kc = 0;
    while (true) {
        int kn = kc + 64;
        if (kn < kend) load_k(kB, kn);
        process(kA, kc);
        kc = kn;
        if (kc >= kend) break;
        kn = kc + 64;
        if (kn < kend) load_k(kA, kn);
        process(kB, kc);
        kc = kn;
        if (kc >= kend) break;
    }

    // ---- epilogue: y / l, pack pairs, store to [B,T,C] ----
    {
        const float inv = 1.f / lrun;
        const int t = qbase + lr;
#pragma unroll
        for (int n = 0; n < 4; n++) {
#pragma unroll
            for (int rp = 0; rp < 2; rp++) {
                u32 dw = cvt_pk_bf16(yacc[n][2 * rp] * inv, yacc[n][2 * rp + 1] * inv);
                const int d = n * 16 + 4 * lg + 2 * rp;
                *(u32*)&Yb[((size_t)(b * T_DIM + t)) * C_DIM + h * 64 + d] = dw;
            }
        }
    }
}

// ---------------- launch ----------------
extern "C" void kernel_launch(void* const* d_in, const int* in_sizes, int n_in,
                              void* d_out, int out_size, void* d_ws, size_t ws_size,
                              hipStream_t stream) {
    const float* x      = (const float*)d_in[0];
    const float* W_attn = (const float*)d_in[1];
    const float* b_attn = (const float*)d_in[2];
    const float* W_proj = (const float*)d_in[3];
    const float* b_proj = (const float*)d_in[4];
    float* out = (float*)d_out;

    char* ws = (char*)d_ws;
    // offsets (bytes), all 256-aligned
    u16* xb  = (u16*)(ws);                       //  4096x768   bf16  (x)
    u16* WtA = (u16*)(ws + 6291456);             //  2304x768   bf16  (W_attn^T)
    u16* WtP = (u16*)(ws + 9830400);             //   768x768   bf16  (W_proj^T)
    u16* Qb  = (u16*)(ws + 11010048);            //  [B,H,T,D]  bf16  (pre-scaled by 0.125*log2e)
    u16* Kb  = (u16*)(ws + 17301504);            //  [B,H,T,D]  bf16
    u16* Vt  = (u16*)(ws + 23592960);            //  [B,H,D,T]  bf16
    u16* Yb  = (u16*)(ws + 29884416);            //  4096x768   bf16  (attn out)

    // 1) convert x to bf16
    convert_bf16<<<3072, 256, 0, stream>>>(x, xb);
    // 2) transpose+convert weights
    transpose_bf16<<<dim3(2304 / 32, 768 / 32), dim3(32, 8), 0, stream>>>(W_attn, WtA, 768, 2304);
    transpose_bf16<<<dim3(768 / 32, 768 / 32), dim3(32, 8), 0, stream>>>(W_proj, WtP, 768, 768);
    // 3) QKV GEMM + scatter (BN=64 -> 1152 blocks)
    gemm_bt<0, 2><<<dim3(2304 / 64, 4096 / 128), 256, 0, stream>>>(xb, WtA, b_attn, Qb, Kb, Vt, nullptr);
    // 4) causal flash attention (1 wave / 16 q-rows, LPT dispatch order)
    attn_kernel<<<dim3(B_DIM * H_DIM, T_DIM / 16), 64, 0, stream>>>(Qb, Kb, Vt, Yb);
    // 5) proj GEMM -> fp32 out (BN=64 -> 384 blocks)
    gemm_bt<1, 2><<<dim3(768 / 64, 4096 / 128), 256, 0, stream>>>(Yb, WtP, b_proj, nullptr, nullptr, nullptr, out);
}

// Round 4
// 146.445 us; speedup vs baseline: 1.4079x; 1.4079x over previous
//
#include <hip/hip_runtime.h>

typedef unsigned short u16;
typedef unsigned int   u32;
typedef __bf16 bf16x8 __attribute__((ext_vector_type(8)));
typedef float  f32x4  __attribute__((ext_vector_type(4)));

#define B_DIM 2
#define T_DIM 2048
#define C_DIM 768
#define H_DIM 12
#define D_DIM 64
#define KD 768  // GEMM K dim (= C)

__device__ __forceinline__ u16 f2bf(float f) {
    union { float f; u32 u; } v; v.f = f;
    u32 r = v.u + 0x7FFFu + ((v.u >> 16) & 1u);   // RNE
    return (u16)(r >> 16);
}

__device__ __forceinline__ u32 cvt_pk_bf16(float lo, float hi) {
    u32 r;
    asm("v_cvt_pk_bf16_f32 %0, %1, %2" : "=v"(r) : "v"(lo), "v"(hi));
    return r;
}

__device__ __forceinline__ float exp2_hw(float x) {
    float r;
    asm("v_exp_f32 %0, %1" : "=v"(r) : "v"(x));
    return r;
}

__device__ __forceinline__ void load_lds16(const void* g, void* l) {
    __builtin_amdgcn_global_load_lds(
        (const __attribute__((address_space(1))) u32*)g,
        (__attribute__((address_space(3))) u32*)l,
        16, 0, 0);
}

// ---------------- fp32 -> bf16 convert (x) ----------------
__global__ __launch_bounds__(256) void convert_bf16(const float* __restrict__ in,
                                                    u16* __restrict__ out) {
    int i = blockIdx.x * blockDim.x + threadIdx.x;
    float4 v = ((const float4*)in)[i];
    ushort4 o;
    o.x = f2bf(v.x); o.y = f2bf(v.y); o.z = f2bf(v.z); o.w = f2bf(v.w);
    ((ushort4*)out)[i] = o;
}

// ---------------- W [K][N] fp32 -> Wt [N][K] bf16 ----------------
__global__ __launch_bounds__(256) void transpose_bf16(const float* __restrict__ W,
                                                      u16* __restrict__ Wt,
                                                      int K, int N) {
    __shared__ float tile[32][33];
    int bx = blockIdx.x * 32, by = blockIdx.y * 32;
    int tx = threadIdx.x, ty = threadIdx.y;
#pragma unroll
    for (int i = ty; i < 32; i += 8) tile[i][tx] = W[(size_t)(by + i) * N + bx + tx];
    __syncthreads();
#pragma unroll
    for (int i = ty; i < 32; i += 8) Wt[(size_t)(bx + i) * K + by + tx] = f2bf(tile[tx][i]);
}

// ---------------- GEMM: A[M][768] bf16 @ Bt[N][768]^T, 128 x (NJ*32) tile, BK=64 ----------------
template <int EPI, int NJ>
__global__ __launch_bounds__(256)
void gemm_bt(const u16* __restrict__ A, const u16* __restrict__ Bt,
             const float* __restrict__ bias,
             u16* __restrict__ Qb, u16* __restrict__ Kb, u16* __restrict__ Vt,
             float* __restrict__ Cout) {
    __shared__ u16 lA[128 * 64];
    __shared__ u16 lB[NJ * 32 * 64];
    const int tid  = threadIdx.x;
    const int lane = tid & 63, wv = tid >> 6;
    const int lr = lane & 15, lg = lane >> 4;
    const int wm = wv >> 1, wn = wv & 1;
    const int row0 = blockIdx.y * 128, col0 = blockIdx.x * (NJ * 32);

    const f32x4 Z4 = {0.f, 0.f, 0.f, 0.f};
    f32x4 acc[4][NJ];
#pragma unroll
    for (int i = 0; i < 4; i++)
#pragma unroll
        for (int j = 0; j < NJ; j++) acc[i][j] = Z4;

    for (int kt = 0; kt < KD / 64; ++kt) {
#pragma unroll
        for (int i = 0; i < 4; i++) {               // A: 16 chunks of 1KB
            int chunk = wv * 4 + i;
            int row = chunk * 8 + (lane >> 3);
            int el  = (lane & 7) * 8;
            load_lds16(&A[(size_t)(row0 + row) * KD + kt * 64 + el], &lA[chunk * 512]);
        }
#pragma unroll
        for (int i = 0; i < NJ; i++) {              // B: NJ*4 chunks of 1KB
            int chunk = wv * NJ + i;
            int row = chunk * 8 + (lane >> 3);
            int el  = (lane & 7) * 8;
            load_lds16(&Bt[(size_t)(col0 + row) * KD + kt * 64 + el], &lB[chunk * 512]);
        }
        __syncthreads();
#pragma unroll
        for (int kk = 0; kk < 2; kk++) {
            bf16x8 af[4], bfr[NJ];
#pragma unroll
            for (int i = 0; i < 4; i++)
                af[i] = *(const bf16x8*)&lA[(wm * 64 + i * 16 + lr) * 64 + kk * 32 + lg * 8];
#pragma unroll
            for (int j = 0; j < NJ; j++)
                bfr[j] = *(const bf16x8*)&lB[(wn * (NJ * 16) + j * 16 + lr) * 64 + kk * 32 + lg * 8];
#pragma unroll
            for (int i = 0; i < 4; i++)
#pragma unroll
                for (int j = 0; j < NJ; j++)
                    acc[i][j] = __builtin_amdgcn_mfma_f32_16x16x32_bf16(af[i], bfr[j], acc[i][j], 0, 0, 0);
        }
        __syncthreads();
    }

    if (EPI == 0) {
        const int b  = row0 >> 11;
        const int t0 = (row0 & 2047) + wm * 64;
        const float qscale = 0.125f * 1.44269504088896340736f;  // fold log2(e)
#pragma unroll
        for (int i = 0; i < 4; i++) {
#pragma unroll
            for (int j = 0; j < NJ; j++) {
                const int n   = col0 + wn * (NJ * 16) + j * 16 + lr;
                const int seg = n / 768;
                const int nn  = n - seg * 768;
                const int h   = nn >> 6;
                const int d   = nn & 63;
                const float bv = bias[n];
#pragma unroll
                for (int r = 0; r < 4; r++) {
                    const int t = t0 + i * 16 + lg * 4 + r;
                    float v = acc[i][j][r] + bv;
                    if (seg == 0) {
                        Qb[((size_t)(b * H_DIM + h) * T_DIM + t) * D_DIM + d] = f2bf(v * qscale);
                    } else if (seg == 1) {
                        Kb[((size_t)(b * H_DIM + h) * T_DIM + t) * D_DIM + d] = f2bf(v);
                    } else {
                        Vt[((size_t)(b * H_DIM + h) * D_DIM + d) * T_DIM + t] = f2bf(v);
                    }
                }
            }
        }
    } else {
#pragma unroll
        for (int i = 0; i < 4; i++)
#pragma unroll
            for (int j = 0; j < NJ; j++) {
                const int n  = col0 + wn * (NJ * 16) + j * 16 + lr;
                const float bv = bias[n];
#pragma unroll
                for (int r = 0; r < 4; r++) {
                    const int m = row0 + wm * 64 + i * 16 + lg * 4 + r;
                    Cout[(size_t)m * 768 + n] = acc[i][j][r] + bv;
                }
            }
    }
}

// ---------------- causal flash attention (swapped-operand, zero-LDS, 2-stage pipeline) ----------------
// 1 wave per block, 32 q-rows per wave.  grid (B*H, T/32), LPT order.
// Pipeline: QK(t+1) issued before finish(t) -> MFMA of next tile overlaps softmax VALU of current.
struct KTile { bf16x8 k[4][2]; };
struct VTile { ushort4 v[4][2][2]; };   // [d-tile n][K32-step s][chunk]
union VFrag  { struct { ushort4 lo, hi; } s; bf16x8 v; };
union PFrag  { u32 w[4]; bf16x8 v; };

__global__ __launch_bounds__(64)
void attn_kernel(const u16* __restrict__ Qb, const u16* __restrict__ Kb,
                 const u16* __restrict__ Vt, u16* __restrict__ Yb) {
    const int bh    = blockIdx.x;
    const int chunk = (int)gridDim.y - 1 - blockIdx.y;   // LPT: longest q-chunks first
    const int b = bh / H_DIM, h = bh % H_DIM;
    const int lane = threadIdx.x;
    const int lr = lane & 15, lg = lane >> 4;
    const int qbase = chunk * 32;
    const int kend  = qbase + 32;
    const int nt    = (kend + 63) >> 6;   // 64-wide k-tiles (last may be causally part-masked)

    const u16* Qp = Qb + (size_t)bh * T_DIM * D_DIM;
    const u16* Kp = Kb + (size_t)bh * T_DIM * D_DIM;
    const u16* Vp = Vt + (size_t)bh * D_DIM * T_DIM;

    // Q fragments (B-operand): col = lr = q-within-16, contraction d = lg*8+j
    bf16x8 qf[2][2];
#pragma unroll
    for (int m = 0; m < 2; m++)
#pragma unroll
        for (int dh = 0; dh < 2; dh++)
            qf[m][dh] = *(const bf16x8*)&Qp[(size_t)(qbase + m * 16 + lr) * 64 + dh * 32 + lg * 8];

    const f32x4 Z4 = {0.f, 0.f, 0.f, 0.f};
    f32x4 yacc[2][4];                  // [m][n]: col q = lr, row d = n*16 + 4*lg + r
    float mrun[2] = {-1e30f, -1e30f};
    float lrun[2] = {0.f, 0.f};
#pragma unroll
    for (int m = 0; m < 2; m++)
#pragma unroll
        for (int n = 0; n < 4; n++) yacc[m][n] = Z4;

    auto load_k = [&](KTile& kt, int kc) {
#pragma unroll
        for (int kf = 0; kf < 4; kf++)
#pragma unroll
            for (int dh = 0; dh < 2; dh++)
                kt.k[kf][dh] = *(const bf16x8*)&Kp[(size_t)(kc + kf * 16 + lr) * 64 + dh * 32 + lg * 8];
    };
    auto load_v = [&](VTile& vt, int kc) {
#pragma unroll
        for (int n = 0; n < 4; n++)
#pragma unroll
            for (int s = 0; s < 2; s++)
#pragma unroll
                for (int c = 0; c < 2; c++)
                    vt.v[n][s][c] = *(const ushort4*)&Vp[(size_t)(n * 16 + lr) * T_DIM + kc + 32 * s + 16 * c + 4 * lg];
    };
    auto qk = [&](KTile& kt, f32x4 (&S)[2][4]) {
#pragma unroll
        for (int m = 0; m < 2; m++)
#pragma unroll
            for (int kf = 0; kf < 4; kf++) S[m][kf] = Z4;
        __builtin_amdgcn_s_setprio(1);
#pragma unroll
        for (int kf = 0; kf < 4; kf++)
#pragma unroll
            for (int m = 0; m < 2; m++) {
                S[m][kf] = __builtin_amdgcn_mfma_f32_16x16x32_bf16(kt.k[kf][0], qf[m][0], S[m][kf], 0, 0, 0);
                S[m][kf] = __builtin_amdgcn_mfma_f32_16x16x32_bf16(kt.k[kf][1], qf[m][1], S[m][kf], 0, 0, 0);
            }
        __builtin_amdgcn_s_setprio(0);
    };
    // finish tile at kc: mask, online softmax (defer-max), pack P, PV
    auto finish = [&](f32x4 (&S)[2][4], VTile& vt, int kc) {
        if (kc + 63 > qbase) {
#pragma unroll
            for (int m = 0; m < 2; m++) {
                const int q = qbase + m * 16 + lr;
#pragma unroll
                for (int kf = 0; kf < 4; kf++)
#pragma unroll
                    for (int r = 0; r < 4; r++) {
                        const int k = kc + kf * 16 + 4 * lg + r;
                        if (k > q) S[m][kf][r] = -1e30f;
                    }
            }
        }
        PFrag pf[2][2];
#pragma unroll
        for (int m = 0; m < 2; m++) {
            float mx = -1e30f;
#pragma unroll
            for (int kf = 0; kf < 4; kf++) {
                float a = fmaxf(S[m][kf][0], S[m][kf][1]);
                float c = fmaxf(S[m][kf][2], S[m][kf][3]);
                mx = fmaxf(mx, fmaxf(a, c));
            }
            mx = fmaxf(mx, __shfl_xor(mx, 16));
            mx = fmaxf(mx, __shfl_xor(mx, 32));
            // defer-max (T13): only rescale when the tile max meaningfully exceeds running max
            if (!__all(mx <= mrun[m] + 8.0f)) {
                float mnew = fmaxf(mrun[m], mx);
                float sfr  = exp2_hw(mrun[m] - mnew);
                mrun[m] = mnew;
                lrun[m] *= sfr;
#pragma unroll
                for (int n = 0; n < 4; n++)
#pragma unroll
                    for (int r = 0; r < 4; r++) yacc[m][n][r] *= sfr;
            }
            float sum = 0.f;
#pragma unroll
            for (int kf = 0; kf < 4; kf++)
#pragma unroll
                for (int r = 0; r < 4; r++) {
                    float p = exp2_hw(S[m][kf][r] - mrun[m]);
                    S[m][kf][r] = p;
                    sum += p;
                }
            sum += __shfl_xor(sum, 16);
            sum += __shfl_xor(sum, 32);
            lrun[m] += sum;
#pragma unroll
            for (int s = 0; s < 2; s++) {
                pf[m][s].w[0] = cvt_pk_bf16(S[m][2 * s][0],     S[m][2 * s][1]);
                pf[m][s].w[1] = cvt_pk_bf16(S[m][2 * s][2],     S[m][2 * s][3]);
                pf[m][s].w[2] = cvt_pk_bf16(S[m][2 * s + 1][0], S[m][2 * s + 1][1]);
                pf[m][s].w[3] = cvt_pk_bf16(S[m][2 * s + 1][2], S[m][2 * s + 1][3]);
            }
        }
        __builtin_amdgcn_s_setprio(1);
#pragma unroll
        for (int s = 0; s < 2; s++)
#pragma unroll
            for (int n = 0; n < 4; n++) {
                VFrag av;
                av.s.lo = vt.v[n][s][0];
                av.s.hi = vt.v[n][s][1];
#pragma unroll
                for (int m = 0; m < 2; m++)
                    yacc[m][n] = __builtin_amdgcn_mfma_f32_16x16x32_bf16(av.v, pf[m][s].v, yacc[m][n], 0, 0, 0);
            }
        __builtin_amdgcn_s_setprio(0);
    };

    // ---- 2-stage pipelined k-loop (explicit ping-pong, no dynamic indexing) ----
    KTile kA, kB;
    VTile vA, vB;
    f32x4 SP[2][4], SN[2][4];

    load_k(kA, 0);
    load_v(vA, 0);
    qk(kA, SP);                         // tile 0 scores
    if (nt > 1) { load_k(kB, 64); load_v(vB, 64); }

    int t = 0;
    for (;;) {
        // phase A: pending tile t in SP (V in vA); next K in kB
        if (t + 1 < nt) qk(kB, SN);                 // MFMA of t+1 overlaps softmax of t
        if (t + 2 < nt) load_k(kA, 64 * (t + 2));   // kA regs free (SP already computed)
        finish(SP, vA, 64 * t);
        if (t + 2 < nt) load_v(vA, 64 * (t + 2));
        if (++t >= nt) break;
        // phase B: mirror
        if (t + 1 < nt) qk(kA, SP);
        if (t + 2 < nt) load_k(kB, 64 * (t + 2));
        finish(SN, vB, 64 * t);
        if (t + 2 < nt) load_v(vB, 64 * (t + 2));
        if (++t >= nt) break;
    }

    // ---- epilogue: y / l, pack pairs, store to [B,T,C] ----
#pragma unroll
    for (int m = 0; m < 2; m++) {
        const float inv = 1.f / lrun[m];
        const int t2 = qbase + m * 16 + lr;
#pragma unroll
        for (int n = 0; n < 4; n++) {
#pragma unroll
            for (int rp = 0; rp < 2; rp++) {
                u32 dw = cvt_pk_bf16(yacc[m][n][2 * rp] * inv, yacc[m][n][2 * rp + 1] * inv);
                const int d = n * 16 + 4 * lg + 2 * rp;
                *(u32*)&Yb[((size_t)(b * T_DIM + t2)) * C_DIM + h * 64 + d] = dw;
            }
        }
    }
}

// ---------------- launch ----------------
extern "C" void kernel_launch(void* const* d_in, const int* in_sizes, int n_in,
                              void* d_out, int out_size, void* d_ws, size_t ws_size,
                              hipStream_t stream) {
    const float* x      = (const float*)d_in[0];
    const float* W_attn = (const float*)d_in[1];
    const float* b_attn = (const float*)d_in[2];
    const float* W_proj = (const float*)d_in[3];
    const float* b_proj = (const float*)d_in[4];
    float* out = (float*)d_out;

    char* ws = (char*)d_ws;
    u16* xb  = (u16*)(ws);                       //  4096x768   bf16  (x)
    u16* WtA = (u16*)(ws + 6291456);             //  2304x768   bf16  (W_attn^T)
    u16* WtP = (u16*)(ws + 9830400);             //   768x768   bf16  (W_proj^T)
    u16* Qb  = (u16*)(ws + 11010048);            //  [B,H,T,D]  bf16  (pre-scaled by 0.125*log2e)
    u16* Kb  = (u16*)(ws + 17301504);            //  [B,H,T,D]  bf16
    u16* Vt  = (u16*)(ws + 23592960);            //  [B,H,D,T]  bf16
    u16* Yb  = (u16*)(ws + 29884416);            //  4096x768   bf16  (attn out)

    convert_bf16<<<3072, 256, 0, stream>>>(x, xb);
    transpose_bf16<<<dim3(2304 / 32, 768 / 32), dim3(32, 8), 0, stream>>>(W_attn, WtA, 768, 2304);
    transpose_bf16<<<dim3(768 / 32, 768 / 32), dim3(32, 8), 0, stream>>>(W_proj, WtP, 768, 768);
    gemm_bt<0, 2><<<dim3(2304 / 64, 4096 / 128), 256, 0, stream>>>(xb, WtA, b_attn, Qb, Kb, Vt, nullptr);
    attn_kernel<<<dim3(B_DIM * H_DIM, T_DIM / 32), 64, 0, stream>>>(Qb, Kb, Vt, Yb);
    gemm_bt<1, 2><<<dim3(768 / 64, 4096 / 128), 256, 0, stream>>>(Yb, WtP, b_proj, nullptr, nullptr, nullptr, out);
}